// Round 2
// baseline (226.352 us; speedup 1.0000x reference)
//
#include <hip/hip_runtime.h>
#include <math.h>

// BERT-CRF forward NLL on MI355X — register-only serial recursion, one item
// per 64-lane wave, p duplicated mod 32 across halves.
//
// This revision removes ALL serial cross-lane dependencies from the step:
//  - DPP row_ror:N (N=1..15) reaches every same-16-block source in ONE
//    independent DPP from p (no rotl->rotl chains).
//  - The complement block is served by a second state register p16
//    (p16[lane j] = P[(j+16)&31]), maintained RECURSIVELY: the same 30
//    rotated registers feed a second accumulator pair with coefficient
//    tables permuted to destination d^16. No ds_swizzle, no LDS in loop.
// Per-step: 30 independent DPP + 64 FMA + ~20 misc VALU => issue-bound.
//
// Source coverage per dest lane j (d = j&31):
//   row_ror:N of p   -> tag (d&16)|((d-N)&15)   == d's 16-block, all 16
//   row_ror:N of p16 -> the same ^16            == complement block, all 16

constexpr int NTAG = 32;
constexpr int TSTART = 30;
constexpr int TSTOP = 31;
constexpr int NB = 1024;
constexpr int NS = 512;

constexpr float LOG2E = 1.44269504088896340736f;
constexpr float LN2   = 0.69314718055994530942f;

__device__ __forceinline__ float fexp2(float x) {
#if __has_builtin(__builtin_amdgcn_exp2f)
    return __builtin_amdgcn_exp2f(x);
#else
    return exp2f(x);
#endif
}

__global__ __launch_bounds__(64)
void crf_fwd(const float* __restrict__ feats,
             const int*   __restrict__ labels,
             const int*   __restrict__ lengths,
             const float* __restrict__ trans,
             float*       __restrict__ out)
{
    const int j   = threadIdx.x;   // 0..63
    const int j32 = j & 31;
    const int b   = blockIdx.x;

    const int d   = j32;           // destination tag for p accumulation
    const int d16 = j32 ^ 16;      // destination tag for p16 accumulation

    // Coefficient tables (exp of trans), indexed by row_ror amount N.
    //   srcP(N) = (d&16)|((d-N)&15)      (same 16-block as d)
    //   srcQ(N) = srcP(N)^16             (complement block)
    // EP/EQ accumulate p_new (dest d); GP/GQ accumulate p16_new (dest d^16).
    float EP[16], EQ[16], GP[16], GQ[16];
    #pragma unroll
    for (int N = 0; N < 16; ++N) {
        int sp = (d & 16) | ((d - N) & 15);
        int sq = sp ^ 16;
        EP[N] = fexp2(trans[(sp << 5) + d]   * LOG2E);
        EQ[N] = fexp2(trans[(sq << 5) + d]   * LOG2E);
        GP[N] = fexp2(trans[(sp << 5) + d16] * LOG2E);
        GQ[N] = fexp2(trans[(sq << 5) + d16] * LOG2E);
    }

    const int len = lengths[b];
    const float* fb = feats  + (size_t)b * NS * NTAG;
    const int*   lb = labels + (size_t)b * NS;

    // labels for this item, staged into registers (coalesced, off the loop)
    int labr[8];
    #pragma unroll
    for (int k = 0; k < 8; ++k)
        labr[k] = lb[(k << 6) + j];

    // t = 0 : init both states
    float p   = fexp2((fb[d]   + trans[(TSTART << 5) + d])   * LOG2E);
    float p16 = fexp2((fb[d16] + trans[(TSTART << 5) + d16]) * LOG2E);

    int bits0 = __builtin_amdgcn_readfirstlane(__float_as_int(p));
    int e0    = min(max((bits0 >> 23) & 0xFF, 1), 254);
    int kreg  = e0 - 127;
    int creg  = 0;

    // feats prefetch pipelines (8 deep), one per state
    float pf[8], pf16[8];
    #pragma unroll
    for (int u = 0; u < 8; ++u) {
        int tt = min(1 + u, NS - 1);
        pf[u]   = fb[(size_t)tt * NTAG + d];
        pf16[u] = fb[(size_t)tt * NTAG + d16];
    }

    const int nsteps = len - 1;        // recursion steps t = 1..len-1
    const int nchunk = nsteps >> 3;
    const int rem    = nsteps & 7;
    int t = 1;

    // One independent DPP pair per N; each rotated value feeds 2 FMAs.
    #define ROT_TERM(N)                                                      \
    {                                                                        \
        float rp = __int_as_float(__builtin_amdgcn_update_dpp(               \
            0, __float_as_int(p),   0x120 + N, 0xF, 0xF, false));            \
        float rq = __int_as_float(__builtin_amdgcn_update_dpp(               \
            0, __float_as_int(p16), 0x120 + N, 0xF, 0xF, false));            \
        a0 = fmaf(rp, EP[N], a0);  a1 = fmaf(rq, EQ[N], a1);                 \
        b0 = fmaf(rp, GP[N], b0);  b1 = fmaf(rq, GQ[N], b1);                 \
    }

    #define CRF_STEP(FEAT, FEAT16)                                           \
    {                                                                        \
        /* off-chain: emission factors with folded 2^-k */                   \
        creg += kreg;                                                        \
        float kf  = (float)kreg;                                             \
        float F   = fexp2(fmaf((FEAT),   LOG2E, -kf));                       \
        float F16 = fexp2(fmaf((FEAT16), LOG2E, -kf));                       \
        /* 30 independent DPPs + 64 FMAs into 4 accumulators */              \
        float a0 = p * EP[0],  a1 = p16 * EQ[0];                             \
        float b0 = p * GP[0],  b1 = p16 * GQ[0];                             \
        ROT_TERM(1)  ROT_TERM(2)  ROT_TERM(3)  ROT_TERM(4)                   \
        ROT_TERM(5)  ROT_TERM(6)  ROT_TERM(7)  ROT_TERM(8)                   \
        ROT_TERM(9)  ROT_TERM(10) ROT_TERM(11) ROT_TERM(12)                  \
        ROT_TERM(13) ROT_TERM(14) ROT_TERM(15)                               \
        float qv  = a0 + a1;                                                 \
        float q16 = b0 + b1;                                                 \
        p   = qv  * F;                                                       \
        p16 = q16 * F16;                                                     \
        /* renorm bookkeeping for next step (off next chain) */              \
        int bits_ = __builtin_amdgcn_readfirstlane(__float_as_int(p));       \
        int e_ = min(max((bits_ >> 23) & 0xFF, 1), 254);                     \
        kreg = e_ - 127;                                                     \
    }

    for (int ci = 0; ci < nchunk; ++ci) {
        #pragma unroll
        for (int u = 0; u < 8; ++u) {
            float feat   = pf[u];
            float feat16 = pf16[u];
            int   tp     = min(t + 8, NS - 1);
            pf[u]   = fb[(size_t)tp * NTAG + d];       // prefetch t+8
            pf16[u] = fb[(size_t)tp * NTAG + d16];
            CRF_STEP(feat, feat16)
            ++t;
        }
    }
    // remainder (<8 steps); pf[u] holds feats for t = 1+8*nchunk+u
    #pragma unroll
    for (int u = 0; u < 7; ++u) {
        if (u < rem) {
            CRF_STEP(pf[u], pf16[u])
            ++t;
        }
    }
    #undef CRF_STEP
    #undef ROT_TERM

    // forward score = c*ln2 + log(sum_j p[j]); p duplicated mod 32, so the
    // xor butterfly over masks 1..16 sums the 32 distinct entries.
    float s = p;
    #pragma unroll
    for (int m = 1; m <= 16; m <<= 1)
        s += __shfl_xor(s, m, 64);
    float fwd = (float)creg * LN2 + logf(s);

    // ---- gold score: parallel gather tail (latency-tolerant) ----
    float gold = 0.0f;
    #pragma unroll
    for (int k = 0; k < 8; ++k) {
        int tt = (k << 6) + j;
        if (tt < len) {
            int lab_t = labr[k];
            gold += fb[(size_t)tt * NTAG + lab_t];               // emit
            if (tt > 0)
                gold += trans[(lb[tt - 1] << 5) + lab_t];        // pair
            else
                gold += trans[(TSTART << 5) + lab_t];            // start
            if (tt == len - 1)
                gold += trans[(lab_t << 5) + TSTOP];             // stop
        }
    }
    // reduce gold over all 64 lanes (each (b,t) counted once)
    #pragma unroll
    for (int m = 1; m <= 32; m <<= 1)
        gold += __shfl_xor(gold, m, 64);

    if (j == 0)
        atomicAdd(out, (fwd - gold) * (1.0f / 1024.0f));
}

extern "C" void kernel_launch(void* const* d_in, const int* in_sizes, int n_in,
                              void* d_out, int out_size, void* d_ws, size_t ws_size,
                              hipStream_t stream) {
    const float* feats   = (const float*)d_in[0];
    const int*   labels  = (const int*)d_in[1];
    const int*   lengths = (const int*)d_in[2];
    const float* trans   = (const float*)d_in[3];
    float*       out     = (float*)d_out;

    hipMemsetAsync(out, 0, sizeof(float) * (size_t)out_size, stream);
    crf_fwd<<<dim3(NB), dim3(64), 0, stream>>>(feats, labels, lengths, trans, out);
}

// Round 3
// 185.760 us; speedup vs baseline: 1.2185x; 1.2185x over previous
//
#include <hip/hip_runtime.h>
#include <math.h>

// BERT-CRF forward NLL on MI355X — register-only serial recursion, one item
// per 64-lane wave, p duplicated mod 32 across halves.
//
// Round-2 revision, attacking the measured disease (VALUBusy pinned ~33% in
// all prior variants => dependent-FMA latency exposed, stall ~ 2x issue):
//  - SINGLE state p. Same-16-block sources via 15 independent row_ror DPPs;
//    complement block via ONE ds_swizzle xor-16 per step (x16[j] = p[j^16])
//    followed by 15 row_ror DPPs of x16. Halves the FMA count vs round 1
//    (32 vs 64) and drops the second exp + second prefetch stream.
//  - Accumulation in 8 INDEPENDENT 4-deep FMA sub-chains (4 for the p-block,
//    4 for the x16-block), combined by a 3-level add tree. Max dependent
//    depth 4 (was 16) with 8 interleaved streams => latency hidden by issue.
//  - The swizzle is issued first; its ~40-60 cyc LDS latency is covered by
//    the 15 p-DPPs + 16 p-FMAs issued before its first consumer.
//
// Source coverage per dest lane j (d = j&31):
//   row_ror:N of p   -> tag (d&16)|((d-N)&15), N=0..15  == d's 16-block
//   row_ror:N of x16 -> the same ^16                    == complement block

constexpr int NTAG = 32;
constexpr int TSTART = 30;
constexpr int TSTOP = 31;
constexpr int NB = 1024;
constexpr int NS = 512;

constexpr float LOG2E = 1.44269504088896340736f;
constexpr float LN2   = 0.69314718055994530942f;

__device__ __forceinline__ float fexp2(float x) {
#if __has_builtin(__builtin_amdgcn_exp2f)
    return __builtin_amdgcn_exp2f(x);
#else
    return exp2f(x);
#endif
}
__device__ __forceinline__ float xor16(float x) {  // dst[j] = src[j^16] (32-grp)
    return __int_as_float(__builtin_amdgcn_ds_swizzle(
        __float_as_int(x), 0x401F /*bitmode xor=0x10 and=0x1F*/));
}

__global__ __launch_bounds__(64)
void crf_fwd(const float* __restrict__ feats,
             const int*   __restrict__ labels,
             const int*   __restrict__ lengths,
             const float* __restrict__ trans,
             float*       __restrict__ out)
{
    const int j   = threadIdx.x;   // 0..63
    const int j32 = j & 31;
    const int b   = blockIdx.x;

    const int d = j32;             // destination tag

    // Coefficient tables (exp of trans), indexed by row_ror amount N.
    //   srcP(N) = (d&16)|((d-N)&15)   EP[N] = exp(trans[srcP][d])
    //   srcQ(N) = srcP(N)^16          EQ[N] = exp(trans[srcQ][d])
    float EP[16], EQ[16];
    #pragma unroll
    for (int N = 0; N < 16; ++N) {
        int sp = (d & 16) | ((d - N) & 15);
        int sq = sp ^ 16;
        EP[N] = fexp2(trans[(sp << 5) + d] * LOG2E);
        EQ[N] = fexp2(trans[(sq << 5) + d] * LOG2E);
    }

    const int len = lengths[b];
    const float* fb = feats  + (size_t)b * NS * NTAG;
    const int*   lb = labels + (size_t)b * NS;

    // labels for this item, staged into registers (coalesced, off the loop)
    int labr[8];
    #pragma unroll
    for (int k = 0; k < 8; ++k)
        labr[k] = lb[(k << 6) + j];

    // t = 0
    float p = fexp2((fb[d] + trans[(TSTART << 5) + d]) * LOG2E);

    int bits0 = __builtin_amdgcn_readfirstlane(__float_as_int(p));
    int e0    = min(max((bits0 >> 23) & 0xFF, 1), 254);
    int kreg  = e0 - 127;
    int creg  = 0;

    // feats prefetch pipeline (8 deep)
    float pf[8];
    #pragma unroll
    for (int u = 0; u < 8; ++u) {
        int tt = min(1 + u, NS - 1);
        pf[u] = fb[(size_t)tt * NTAG + d];
    }

    const int nsteps = len - 1;        // recursion steps t = 1..len-1
    const int nchunk = nsteps >> 3;
    const int rem    = nsteps & 7;
    int t = 1;

    // row_ror:N as one independent DPP (dpp_ctrl 0x120+N), N = 1..15 literal.
    #define RORV(SRC, N) __int_as_float(__builtin_amdgcn_update_dpp(          \
        0, __float_as_int(SRC), 0x120 + (N), 0xF, 0xF, false))

    #define CRF_STEP(FEAT)                                                    \
    {                                                                         \
        float x16_ = xor16(p);          /* issued first; latency hidden */    \
        /* off-chain: emission factor with folded 2^-k */                     \
        creg += kreg;                                                         \
        float kf = (float)kreg;                                               \
        float F  = fexp2(fmaf((FEAT), LOG2E, -kf));                           \
        /* same-block: 15 DPPs + 16 terms into 4 sub-chains (depth 4) */      \
        float sa0 = p * EP[0];                                                \
        float rp1 = RORV(p, 1), rp2 = RORV(p, 2), rp3 = RORV(p, 3);           \
        float sa1 = rp1 * EP[1];                                              \
        float sa2 = rp2 * EP[2];                                              \
        float sa3 = rp3 * EP[3];                                              \
        float rp4 = RORV(p, 4), rp5 = RORV(p, 5), rp6 = RORV(p, 6),           \
              rp7 = RORV(p, 7);                                               \
        sa0 = fmaf(rp4, EP[4], sa0);                                          \
        sa1 = fmaf(rp5, EP[5], sa1);                                          \
        sa2 = fmaf(rp6, EP[6], sa2);                                          \
        sa3 = fmaf(rp7, EP[7], sa3);                                          \
        float rp8 = RORV(p, 8), rp9 = RORV(p, 9), rp10 = RORV(p, 10),         \
              rp11 = RORV(p, 11);                                             \
        sa0 = fmaf(rp8,  EP[8],  sa0);                                        \
        sa1 = fmaf(rp9,  EP[9],  sa1);                                        \
        sa2 = fmaf(rp10, EP[10], sa2);                                        \
        sa3 = fmaf(rp11, EP[11], sa3);                                        \
        float rp12 = RORV(p, 12), rp13 = RORV(p, 13), rp14 = RORV(p, 14),     \
              rp15 = RORV(p, 15);                                             \
        sa0 = fmaf(rp12, EP[12], sa0);                                        \
        sa1 = fmaf(rp13, EP[13], sa1);                                        \
        sa2 = fmaf(rp14, EP[14], sa2);                                        \
        sa3 = fmaf(rp15, EP[15], sa3);                                        \
        /* complement block: x16 ready by now; same 4-sub-chain pattern */    \
        float sb0 = x16_ * EQ[0];                                             \
        float rq1 = RORV(x16_, 1), rq2 = RORV(x16_, 2), rq3 = RORV(x16_, 3);  \
        float sb1 = rq1 * EQ[1];                                              \
        float sb2 = rq2 * EQ[2];                                              \
        float sb3 = rq3 * EQ[3];                                              \
        float rq4 = RORV(x16_, 4), rq5 = RORV(x16_, 5), rq6 = RORV(x16_, 6),  \
              rq7 = RORV(x16_, 7);                                            \
        sb0 = fmaf(rq4, EQ[4], sb0);                                          \
        sb1 = fmaf(rq5, EQ[5], sb1);                                          \
        sb2 = fmaf(rq6, EQ[6], sb2);                                          \
        sb3 = fmaf(rq7, EQ[7], sb3);                                          \
        float rq8 = RORV(x16_, 8), rq9 = RORV(x16_, 9), rq10 = RORV(x16_, 10),\
              rq11 = RORV(x16_, 11);                                          \
        sb0 = fmaf(rq8,  EQ[8],  sb0);                                        \
        sb1 = fmaf(rq9,  EQ[9],  sb1);                                        \
        sb2 = fmaf(rq10, EQ[10], sb2);                                        \
        sb3 = fmaf(rq11, EQ[11], sb3);                                        \
        float rq12 = RORV(x16_, 12), rq13 = RORV(x16_, 13),                   \
              rq14 = RORV(x16_, 14), rq15 = RORV(x16_, 15);                   \
        sb0 = fmaf(rq12, EQ[12], sb0);                                        \
        sb1 = fmaf(rq13, EQ[13], sb1);                                        \
        sb2 = fmaf(rq14, EQ[14], sb2);                                        \
        sb3 = fmaf(rq15, EQ[15], sb3);                                        \
        /* 3-level combine tree, then scale */                                \
        float qv = ((sa0 + sa1) + (sa2 + sa3)) + ((sb0 + sb1) + (sb2 + sb3)); \
        p = qv * F;                                                           \
        /* renorm bookkeeping for next step (off next chain) */               \
        int bits_ = __builtin_amdgcn_readfirstlane(__float_as_int(p));        \
        int e_ = min(max((bits_ >> 23) & 0xFF, 1), 254);                      \
        kreg = e_ - 127;                                                      \
    }

    for (int ci = 0; ci < nchunk; ++ci) {
        #pragma unroll
        for (int u = 0; u < 8; ++u) {
            float feat = pf[u];
            int   tp   = min(t + 8, NS - 1);
            pf[u] = fb[(size_t)tp * NTAG + d];         // prefetch t+8
            CRF_STEP(feat)
            ++t;
        }
    }
    // remainder (<8 steps); pf[u] holds feats for t = 1+8*nchunk+u
    #pragma unroll
    for (int u = 0; u < 7; ++u) {
        if (u < rem) {
            CRF_STEP(pf[u])
            ++t;
        }
    }
    #undef CRF_STEP
    #undef RORV

    // forward score = c*ln2 + log(sum_j p[j]); p duplicated mod 32, so the
    // xor butterfly over masks 1..16 sums the 32 distinct entries.
    float s = p;
    #pragma unroll
    for (int m = 1; m <= 16; m <<= 1)
        s += __shfl_xor(s, m, 64);
    float fwd = (float)creg * LN2 + logf(s);

    // ---- gold score: parallel gather tail (latency-tolerant) ----
    float gold = 0.0f;
    #pragma unroll
    for (int k = 0; k < 8; ++k) {
        int tt = (k << 6) + j;
        if (tt < len) {
            int lab_t = labr[k];
            gold += fb[(size_t)tt * NTAG + lab_t];               // emit
            if (tt > 0)
                gold += trans[(lb[tt - 1] << 5) + lab_t];        // pair
            else
                gold += trans[(TSTART << 5) + lab_t];            // start
            if (tt == len - 1)
                gold += trans[(lab_t << 5) + TSTOP];             // stop
        }
    }
    // reduce gold over all 64 lanes (each (b,t) counted once)
    #pragma unroll
    for (int m = 1; m <= 32; m <<= 1)
        gold += __shfl_xor(gold, m, 64);

    if (j == 0)
        atomicAdd(out, (fwd - gold) * (1.0f / 1024.0f));
}

extern "C" void kernel_launch(void* const* d_in, const int* in_sizes, int n_in,
                              void* d_out, int out_size, void* d_ws, size_t ws_size,
                              hipStream_t stream) {
    const float* feats   = (const float*)d_in[0];
    const int*   labels  = (const int*)d_in[1];
    const int*   lengths = (const int*)d_in[2];
    const float* trans   = (const float*)d_in[3];
    float*       out     = (float*)d_out;

    hipMemsetAsync(out, 0, sizeof(float) * (size_t)out_size, stream);
    crf_fwd<<<dim3(NB), dim3(64), 0, stream>>>(feats, labels, lengths, trans, out);
}

// Round 4
// 163.629 us; speedup vs baseline: 1.3833x; 1.1352x over previous
//
#include <hip/hip_runtime.h>
#include <math.h>

// BERT-CRF forward NLL on MI355X — register-only serial recursion, one item
// per 64-lane wave.
//
// Round-3 revision. Measured invariant across rounds 0-2: ~6.0 cyc per
// issued instruction for a lone wave per SIMD, independent of dependency
// structure (VALUBusy pinned 33-35%). => minimize instructions per step.
//
// (a) Half-split: lanes 0-31 hold P[i] (dst i), lanes 32-63 hold P[i^16]
//     (dst i^16). Each lane's 15 row_ror DPPs reach its dst's own 16-source
//     block; the same rotation values are the PARTNER lane's (j^32)
//     complement-block sources, so each lane also accumulates the partner's
//     cross sum. One v_permlane32_swap (VALU, no LDS pipe) exchanges them:
//     partner_val = (r0 + r1) - own  (robust to swap-half convention since
//     both swap inputs are equal: {r0,r1} = {[lo|lo],[hi|hi]} either order).
//     => 15 DPPs (was 30), no ds_swizzle.
// (b) v_pk_fma_f32: 32 FMAs -> 16 packed ops; coefficient pairs prepacked.
// (c) Renorm bookkeeping every 2nd step (exact math regardless of schedule;
//     2-step growth <= ~2^30, far inside f32 range).

constexpr int NTAG = 32;
constexpr int TSTART = 30;
constexpr int TSTOP = 31;
constexpr int NB = 1024;
constexpr int NS = 512;

constexpr float LOG2E = 1.44269504088896340736f;
constexpr float LN2   = 0.69314718055994530942f;

typedef float v2f __attribute__((ext_vector_type(2)));
typedef unsigned int v2u __attribute__((ext_vector_type(2)));

__device__ __forceinline__ float fexp2(float x) {
#if __has_builtin(__builtin_amdgcn_exp2f)
    return __builtin_amdgcn_exp2f(x);
#else
    return exp2f(x);
#endif
}

__device__ __forceinline__ v2f pk_mul(v2f a, v2f b) {
    v2f d;
    asm("v_pk_mul_f32 %0, %1, %2" : "=v"(d) : "v"(a), "v"(b));
    return d;
}
__device__ __forceinline__ v2f pk_fma(v2f a, v2f b, v2f c) {
    v2f d;
    asm("v_pk_fma_f32 %0, %1, %2, %3" : "=v"(d) : "v"(a), "v"(b), "v"(c));
    return d;
}
__device__ __forceinline__ v2f pk_add(v2f a, v2f b) {
    v2f d;
    asm("v_pk_add_f32 %0, %1, %2" : "=v"(d) : "v"(a), "v"(b));
    return d;
}

// (r0, r1) = permlane32_swap(v, v): with equal inputs the two results are
// the lower-half-broadcast and upper-half-broadcast (in some order), so
// partner(lane j) = r0[j] + r1[j] - v[j].
__device__ __forceinline__ float swap32_partner(float v) {
#if __has_builtin(__builtin_amdgcn_permlane32_swap)
    v2u r = __builtin_amdgcn_permlane32_swap(
        __float_as_uint(v), __float_as_uint(v), false, false);
    return (__uint_as_float(r.x) + __uint_as_float(r.y)) - v;
#else
    unsigned a = __float_as_uint(v), b = a;
    asm("s_nop 1\n\tv_permlane32_swap_b32 %0, %1" : "+v"(a), "+v"(b));
    return (__uint_as_float(a) + __uint_as_float(b)) - v;
#endif
}

__global__ __launch_bounds__(64)
void crf_fwd(const float* __restrict__ feats,
             const int*   __restrict__ labels,
             const int*   __restrict__ lengths,
             const float* __restrict__ trans,
             float*       __restrict__ out)
{
    const int j   = threadIdx.x;   // 0..63
    const int j32 = j & 31;
    const int b   = blockIdx.x;

    const int hs = (j & 32) >> 1;      // 0 for lower half, 16 for upper
    const int dl = j32 ^ hs;           // this lane's destination tag

    // Coefficient pairs, indexed by rotation amount N (paired 2N,2N+1).
    //   src(N) = ((j32&16)|((j32-N)&15)) ^ hs   (own-block source for dst dl)
    //   EO[N]  = exp(trans[src][dl])            (own-dst coefficient)
    //   ET[N]  = exp(trans[src][dl^16])         (partner-dst coefficient)
    v2f EO[8], ET[8];
    #pragma unroll
    for (int k = 0; k < 8; ++k) {
        int n0 = 2 * k, n1 = 2 * k + 1;
        int s0 = ((j32 & 16) | ((j32 - n0) & 15)) ^ hs;
        int s1 = ((j32 & 16) | ((j32 - n1) & 15)) ^ hs;
        EO[k].x = fexp2(trans[(s0 << 5) + dl] * LOG2E);
        EO[k].y = fexp2(trans[(s1 << 5) + dl] * LOG2E);
        ET[k].x = fexp2(trans[(s0 << 5) + (dl ^ 16)] * LOG2E);
        ET[k].y = fexp2(trans[(s1 << 5) + (dl ^ 16)] * LOG2E);
    }

    const int len = lengths[b];
    const float* fb = feats  + (size_t)b * NS * NTAG;
    const int*   lb = labels + (size_t)b * NS;

    // labels for this item, staged into registers (coalesced, off the loop)
    int labr[8];
    #pragma unroll
    for (int k = 0; k < 8; ++k)
        labr[k] = lb[(k << 6) + j];

    // t = 0 : lane j holds P[dl]
    float x = fexp2((fb[dl] + trans[(TSTART << 5) + dl]) * LOG2E);

    int bits0 = __builtin_amdgcn_readfirstlane(__float_as_int(x));
    int e0    = min(max((bits0 >> 23) & 0xFF, 1), 254);
    int kreg  = e0 - 127;
    int creg  = 0;

    // feats prefetch pipeline (8 deep), per-lane dst index
    float pf[8];
    #pragma unroll
    for (int u = 0; u < 8; ++u) {
        int tt = min(1 + u, NS - 1);
        pf[u] = fb[(size_t)tt * NTAG + dl];
    }

    const int nsteps = len - 1;        // recursion steps t = 1..len-1
    const int nchunk = nsteps >> 3;
    const int rem    = nsteps & 7;
    int t = 1;

    #define RORV(SRC, N) __int_as_float(__builtin_amdgcn_update_dpp(          \
        0, __float_as_int(SRC), 0x120 + (N), 0xF, 0xF, false))

    // RN = 1: fold 2^-kreg into the emission factor and re-extract kreg.
    #define CRF_STEP(FEAT, RN)                                                \
    {                                                                         \
        float F_;                                                             \
        if (RN) {                                                             \
            creg += kreg;                                                     \
            F_ = fexp2(fmaf((FEAT), LOG2E, -(float)kreg));                    \
        } else {                                                              \
            F_ = fexp2((FEAT) * LOG2E);                                       \
        }                                                                     \
        float x1 = RORV(x, 1),  x2 = RORV(x, 2),  x3 = RORV(x, 3);            \
        float x4 = RORV(x, 4),  x5 = RORV(x, 5),  x6 = RORV(x, 6);            \
        float x7 = RORV(x, 7),  x8 = RORV(x, 8),  x9 = RORV(x, 9);            \
        float x10 = RORV(x, 10), x11 = RORV(x, 11), x12 = RORV(x, 12);        \
        float x13 = RORV(x, 13), x14 = RORV(x, 14), x15 = RORV(x, 15);        \
        v2f R0; R0.x = x;   R0.y = x1;                                        \
        v2f R1; R1.x = x2;  R1.y = x3;                                        \
        v2f R2; R2.x = x4;  R2.y = x5;                                        \
        v2f R3; R3.x = x6;  R3.y = x7;                                        \
        v2f R4; R4.x = x8;  R4.y = x9;                                        \
        v2f R5; R5.x = x10; R5.y = x11;                                       \
        v2f R6; R6.x = x12; R6.y = x13;                                       \
        v2f R7; R7.x = x14; R7.y = x15;                                       \
        v2f a0 = pk_mul(R0, EO[0]);                                           \
        v2f b0 = pk_mul(R0, ET[0]);                                           \
        v2f a1 = pk_mul(R1, EO[1]);                                           \
        v2f b1 = pk_mul(R1, ET[1]);                                           \
        a0 = pk_fma(R2, EO[2], a0);  b0 = pk_fma(R2, ET[2], b0);              \
        a1 = pk_fma(R3, EO[3], a1);  b1 = pk_fma(R3, ET[3], b1);              \
        a0 = pk_fma(R4, EO[4], a0);  b0 = pk_fma(R4, ET[4], b0);              \
        a1 = pk_fma(R5, EO[5], a1);  b1 = pk_fma(R5, ET[5], b1);              \
        a0 = pk_fma(R6, EO[6], a0);  b0 = pk_fma(R6, ET[6], b0);              \
        a1 = pk_fma(R7, EO[7], a1);  b1 = pk_fma(R7, ET[7], b1);              \
        v2f va = pk_add(a0, a1);                                              \
        v2f vb = pk_add(b0, b1);                                              \
        float accOwn = va.x + va.y;                                           \
        float accOth = vb.x + vb.y;                                           \
        float qv = accOwn + swap32_partner(accOth);                           \
        x = qv * F_;                                                          \
        if (RN) {                                                             \
            int bits_ = __builtin_amdgcn_readfirstlane(__float_as_int(x));    \
            int e_ = min(max((bits_ >> 23) & 0xFF, 1), 254);                  \
            kreg = e_ - 127;                                                  \
        }                                                                     \
    }

    for (int ci = 0; ci < nchunk; ++ci) {
        #pragma unroll
        for (int u = 0; u < 8; ++u) {
            float feat = pf[u];
            int   tp   = min(t + 8, NS - 1);
            pf[u] = fb[(size_t)tp * NTAG + dl];        // prefetch t+8
            if (u & 1) { CRF_STEP(feat, 1) }
            else       { CRF_STEP(feat, 0) }
            ++t;
        }
    }
    // remainder (<8 steps); pf[u] holds feats for t = 1+8*nchunk+u
    #pragma unroll
    for (int u = 0; u < 7; ++u) {
        if (u < rem) {
            if (u & 1) { CRF_STEP(pf[u], 1) }
            else       { CRF_STEP(pf[u], 0) }
            ++t;
        }
    }
    #undef CRF_STEP
    #undef RORV

    // forward score = c*ln2 + log(sum p). Lanes 0-31 hold P[0..31]; the xor
    // butterfly over masks 1..16 sums the 32 distinct entries within the
    // lower 32-group (upper group holds a permuted copy, also sums fine).
    float s = x;
    #pragma unroll
    for (int m = 1; m <= 16; m <<= 1)
        s += __shfl_xor(s, m, 64);
    float fwd = (float)creg * LN2 + logf(s);

    // ---- gold score: parallel gather tail (latency-tolerant) ----
    float gold = 0.0f;
    #pragma unroll
    for (int k = 0; k < 8; ++k) {
        int tt = (k << 6) + j;
        if (tt < len) {
            int lab_t = labr[k];
            gold += fb[(size_t)tt * NTAG + lab_t];               // emit
            if (tt > 0)
                gold += trans[(lb[tt - 1] << 5) + lab_t];        // pair
            else
                gold += trans[(TSTART << 5) + lab_t];            // start
            if (tt == len - 1)
                gold += trans[(lab_t << 5) + TSTOP];             // stop
        }
    }
    // reduce gold over all 64 lanes (each (b,t) counted once)
    #pragma unroll
    for (int m = 1; m <= 32; m <<= 1)
        gold += __shfl_xor(gold, m, 64);

    if (j == 0)
        atomicAdd(out, (fwd - gold) * (1.0f / 1024.0f));
}

extern "C" void kernel_launch(void* const* d_in, const int* in_sizes, int n_in,
                              void* d_out, int out_size, void* d_ws, size_t ws_size,
                              hipStream_t stream) {
    const float* feats   = (const float*)d_in[0];
    const int*   labels  = (const int*)d_in[1];
    const int*   lengths = (const int*)d_in[2];
    const float* trans   = (const float*)d_in[3];
    float*       out     = (float*)d_out;

    hipMemsetAsync(out, 0, sizeof(float) * (size_t)out_size, stream);
    crf_fwd<<<dim3(NB), dim3(64), 0, stream>>>(feats, labels, lengths, trans, out);
}

// Round 5
// 152.835 us; speedup vs baseline: 1.4810x; 1.0706x over previous
//
#include <hip/hip_runtime.h>
#include <math.h>

// BERT-CRF forward NLL on MI355X — register-only serial recursion, one item
// per 64-lane wave.
//
// Round-4. Measured invariant (r0-r3): lone wave per SIMD issues 1 VALU op
// per ~6 cyc regardless of dependency structure => minimize VALU ops/step.
// r3 computed every matvec product twice (32 products/lane, both halves
// redundant). This version partitions the 1024-product 32x32 matvec
// perfectly across 64 lanes (16 products = 8 pk_fma per lane) using two
// alternating layouts:
//   L1 rows (16-lane) hold tag blocks A,B,A,B  (tag = lane&31)
//   L2 rows hold                     A,A,B,B  (tag = (lane&15)|((lane&32)>>1))
// step-alpha (L1->L2): lane pairs (j, j^16) hold complementary source
//   blocks for a common dst; combine via v_permlane16_swap.
// step-beta  (L2->L1): pairs (j, j^32); combine via v_permlane32_swap.
// Both combines use the order-robust equal-input form partner=(r0+r1)-v.
// Per-step VALU ~= 15 DPP + 8 pk_fma/mul + 1 pk_add + 1 add + 4 combine
// + 1 mul + 2 exp-path + ~1 renorm ~= 35 (was ~63).

constexpr int NTAG = 32;
constexpr int TSTART = 30;
constexpr int TSTOP = 31;
constexpr int NB = 1024;
constexpr int NS = 512;

constexpr float LOG2E = 1.44269504088896340736f;
constexpr float LN2   = 0.69314718055994530942f;

typedef float v2f __attribute__((ext_vector_type(2)));
typedef unsigned int v2u __attribute__((ext_vector_type(2)));

__device__ __forceinline__ float fexp2(float x) {
#if __has_builtin(__builtin_amdgcn_exp2f)
    return __builtin_amdgcn_exp2f(x);
#else
    return exp2f(x);
#endif
}

__device__ __forceinline__ v2f pk_mul(v2f a, v2f b) {
    v2f d;
    asm("v_pk_mul_f32 %0, %1, %2" : "=v"(d) : "v"(a), "v"(b));
    return d;
}
__device__ __forceinline__ v2f pk_fma(v2f a, v2f b, v2f c) {
    v2f d;
    asm("v_pk_fma_f32 %0, %1, %2, %3" : "=v"(d) : "v"(a), "v"(b), "v"(c));
    return d;
}
__device__ __forceinline__ v2f pk_add(v2f a, v2f b) {
    v2f d;
    asm("v_pk_add_f32 %0, %1, %2" : "=v"(d) : "v"(a), "v"(b));
    return d;
}

// Equal-input permlane swaps: outputs partition {v[j], v[partner]}, so
// partner = (r0 + r1) - v regardless of which output is which.
__device__ __forceinline__ float swap32_partner(float v) {
#if __has_builtin(__builtin_amdgcn_permlane32_swap)
    v2u r = __builtin_amdgcn_permlane32_swap(
        __float_as_uint(v), __float_as_uint(v), false, false);
    return (__uint_as_float(r.x) + __uint_as_float(r.y)) - v;
#else
    unsigned a = __float_as_uint(v), b = a;
    asm("v_permlane32_swap_b32 %0, %1" : "+v"(a), "+v"(b));
    return (__uint_as_float(a) + __uint_as_float(b)) - v;
#endif
}
__device__ __forceinline__ float swap16_partner(float v) {
#if __has_builtin(__builtin_amdgcn_permlane16_swap)
    v2u r = __builtin_amdgcn_permlane16_swap(
        __float_as_uint(v), __float_as_uint(v), false, false);
    return (__uint_as_float(r.x) + __uint_as_float(r.y)) - v;
#else
    unsigned a = __float_as_uint(v), b = a;
    asm("v_permlane16_swap_b32 %0, %1" : "+v"(a), "+v"(b));
    return (__uint_as_float(a) + __uint_as_float(b)) - v;
#endif
}

__global__ __launch_bounds__(64)
void crf_fwd(const float* __restrict__ feats,
             const int*   __restrict__ labels,
             const int*   __restrict__ lengths,
             const float* __restrict__ trans,
             float*       __restrict__ out)
{
    const int j   = threadIdx.x;   // 0..63
    const int j32 = j & 31;
    const int b   = blockIdx.x;

    const int i  = j & 15;          // position within 16-lane row
    const int c1 = j & 16;          // row-parity bit (rows 1,3)
    const int c2 = (j & 32) >> 1;   // half bit as tag-block bit (rows 2,3)

    // Coefficient tables, one v2f per rotation pair (N = 2k, 2k+1).
    //   alpha step (L1->L2): src = ((i-N)&15)|c1 , dst-col = i|c2
    //   beta  step (L2->L1): src = ((i-N)&15)|c2 , dst-col = i|c1
    // (rows 0,3: Tm == Ts; rows 1,2: swapped roles)
    v2f Tm[8], Ts[8];
    #pragma unroll
    for (int k = 0; k < 8; ++k) {
        int n0 = 2 * k, n1 = 2 * k + 1;
        int a0s = ((i - n0) & 15), a1s = ((i - n1) & 15);
        Tm[k].x = fexp2(trans[((a0s | c1) << 5) + (i | c2)] * LOG2E);
        Tm[k].y = fexp2(trans[((a1s | c1) << 5) + (i | c2)] * LOG2E);
        Ts[k].x = fexp2(trans[((a0s | c2) << 5) + (i | c1)] * LOG2E);
        Ts[k].y = fexp2(trans[((a1s | c2) << 5) + (i | c1)] * LOG2E);
    }

    const int len = lengths[b];
    const float* fb = feats  + (size_t)b * NS * NTAG;
    const int*   lb = labels + (size_t)b * NS;

    // labels for this item, staged into registers (coalesced, off the loop)
    int labr[8];
    #pragma unroll
    for (int k = 0; k < 8; ++k)
        labr[k] = lb[(k << 6) + j];

    // Emission-factor / prefetch index per step parity:
    //   after alpha (odd t): state layout L2, tag = i|c2
    //   after beta  (even t): layout L1, tag = j32
    const int fxA = i | c2;
    const int fxB = j32;

    // t = 0 : layout L1, lane j holds P0[j32]
    float x = fexp2((fb[j32] + trans[(TSTART << 5) + j32]) * LOG2E);

    int bits0 = __builtin_amdgcn_readfirstlane(__float_as_int(x));
    int e0    = min(max((bits0 >> 23) & 0xFF, 1), 254);
    int kreg  = e0 - 127;
    int creg  = 0;

    // feats prefetch pipeline (8 deep); slot u serves steps t with t%2==(1+u)%2
    float pf[8];
    #pragma unroll
    for (int u = 0; u < 8; ++u) {
        int tt = min(1 + u, NS - 1);
        pf[u] = fb[(size_t)tt * NTAG + ((u & 1) ? fxB : fxA)];
    }

    const int nsteps = len - 1;        // recursion steps t = 1..len-1
    const int nchunk = nsteps >> 3;
    const int rem    = nsteps & 7;
    int t = 1;

    #define RORV(SRC, N) __int_as_float(__builtin_amdgcn_update_dpp(          \
        0, __float_as_int(SRC), 0x120 + (N), 0xF, 0xF, false))

    // TBL: Tm (alpha) or Ts (beta); SW: 16 (alpha) or 32 (beta);
    // RN = 1: fold 2^-kreg into emission factor and re-extract kreg.
    #define CRF_STEP(FEAT, TBL, SW, RN)                                       \
    {                                                                         \
        float F_;                                                             \
        if (RN) {                                                             \
            creg += kreg;                                                     \
            F_ = fexp2(fmaf((FEAT), LOG2E, -(float)kreg));                    \
        } else {                                                              \
            F_ = fexp2((FEAT) * LOG2E);                                       \
        }                                                                     \
        float x1 = RORV(x, 1),  x2 = RORV(x, 2),  x3 = RORV(x, 3);            \
        float x4 = RORV(x, 4),  x5 = RORV(x, 5),  x6 = RORV(x, 6);            \
        float x7 = RORV(x, 7),  x8 = RORV(x, 8),  x9 = RORV(x, 9);            \
        float x10 = RORV(x, 10), x11 = RORV(x, 11), x12 = RORV(x, 12);        \
        float x13 = RORV(x, 13), x14 = RORV(x, 14), x15 = RORV(x, 15);        \
        v2f R0; R0.x = x;   R0.y = x1;                                        \
        v2f R1; R1.x = x2;  R1.y = x3;                                        \
        v2f R2; R2.x = x4;  R2.y = x5;                                        \
        v2f R3; R3.x = x6;  R3.y = x7;                                        \
        v2f R4; R4.x = x8;  R4.y = x9;                                        \
        v2f R5; R5.x = x10; R5.y = x11;                                       \
        v2f R6; R6.x = x12; R6.y = x13;                                       \
        v2f R7; R7.x = x14; R7.y = x15;                                       \
        v2f a0 = pk_mul(R0, TBL[0]);                                          \
        v2f a1 = pk_mul(R1, TBL[1]);                                          \
        a0 = pk_fma(R2, TBL[2], a0);                                          \
        a1 = pk_fma(R3, TBL[3], a1);                                          \
        a0 = pk_fma(R4, TBL[4], a0);                                          \
        a1 = pk_fma(R5, TBL[5], a1);                                          \
        a0 = pk_fma(R6, TBL[6], a0);                                          \
        a1 = pk_fma(R7, TBL[7], a1);                                          \
        v2f va = pk_add(a0, a1);                                              \
        float own = va.x + va.y;                                              \
        float part = (SW == 16) ? swap16_partner(own) : swap32_partner(own);  \
        x = (own + part) * F_;                                                \
        if (RN) {                                                             \
            int bits_ = __builtin_amdgcn_readfirstlane(__float_as_int(x));    \
            int e_ = min(max((bits_ >> 23) & 0xFF, 1), 254);                  \
            kreg = e_ - 127;                                                  \
        }                                                                     \
    }

    for (int ci = 0; ci < nchunk; ++ci) {
        #pragma unroll
        for (int u = 0; u < 8; ++u) {
            float feat = pf[u];
            int   tp   = min(t + 8, NS - 1);
            pf[u] = fb[(size_t)tp * NTAG + ((u & 1) ? fxB : fxA)];
            if (u & 1) { CRF_STEP(feat, Ts, 32, 1) }   // beta, renorm
            else       { CRF_STEP(feat, Tm, 16, 0) }   // alpha
            ++t;
        }
    }
    // remainder (<8 steps); pf[u] holds feats for t = 1+8*nchunk+u
    #pragma unroll
    for (int u = 0; u < 7; ++u) {
        if (u < rem) {
            if (u & 1) { CRF_STEP(pf[u], Ts, 32, 1) }
            else       { CRF_STEP(pf[u], Tm, 16, 0) }
            ++t;
        }
    }
    #undef CRF_STEP
    #undef RORV

    // Every tag appears exactly twice across the 64 lanes in BOTH layouts,
    // so the full 64-lane butterfly gives 2*sum(P); subtract ln2.
    float s = x;
    #pragma unroll
    for (int m = 1; m <= 32; m <<= 1)
        s += __shfl_xor(s, m, 64);
    float fwd = (float)creg * LN2 + logf(s) - LN2;

    // ---- gold score: parallel gather tail (latency-tolerant) ----
    float gold = 0.0f;
    #pragma unroll
    for (int k = 0; k < 8; ++k) {
        int tt = (k << 6) + j;
        if (tt < len) {
            int lab_t = labr[k];
            gold += fb[(size_t)tt * NTAG + lab_t];               // emit
            if (tt > 0)
                gold += trans[(lb[tt - 1] << 5) + lab_t];        // pair
            else
                gold += trans[(TSTART << 5) + lab_t];            // start
            if (tt == len - 1)
                gold += trans[(lab_t << 5) + TSTOP];             // stop
        }
    }
    // reduce gold over all 64 lanes (each (b,t) counted once)
    #pragma unroll
    for (int m = 1; m <= 32; m <<= 1)
        gold += __shfl_xor(gold, m, 64);

    if (j == 0)
        atomicAdd(out, (fwd - gold) * (1.0f / 1024.0f));
}

extern "C" void kernel_launch(void* const* d_in, const int* in_sizes, int n_in,
                              void* d_out, int out_size, void* d_ws, size_t ws_size,
                              hipStream_t stream) {
    const float* feats   = (const float*)d_in[0];
    const int*   labels  = (const int*)d_in[1];
    const int*   lengths = (const int*)d_in[2];
    const float* trans   = (const float*)d_in[3];
    float*       out     = (float*)d_out;

    hipMemsetAsync(out, 0, sizeof(float) * (size_t)out_size, stream);
    crf_fwd<<<dim3(NB), dim3(64), 0, stream>>>(feats, labels, lengths, trans, out);
}

// Round 7
// 133.284 us; speedup vs baseline: 1.6983x; 1.1467x over previous
//
#include <hip/hip_runtime.h>
#include <math.h>

// BERT-CRF forward NLL on MI355X — register-only serial recursion, one item
// per 64-lane wave.
//
// Round-5 (resubmitted unchanged after infra failure). Invariant (r0-r4): a
// lone wave per SIMD retires ~1 VALU instr per ~6-7 cyc regardless of
// dependency structure => minimize EMITTED VALU ops.
// r4's v_pk_* packing cost ~16 v_movs/step of register-pairing tax (measured:
// ~52 emitted vs ~35 designed). This version uses v_fmac_f32 with DPP on
// src0 — rotate+mul+acc in ONE instruction, hand-written asm block:
//   v_mul_f32  acc, x, T[0]
//   v_fmac_f32 acc, x, T[N] row_ror:N     (N = 1..15)
// Single accumulator (dep chains are free under the issue-cadence model).
// Combine across lane pairs simplifies: own+partner == r0+r1 of the
// equal-input permlane swap, so x = (r0 + r1) * F.
// Layouts/tables/renorm/prefetch/gold preserved from the PASSING r4 kernel:
//   L1 rows hold tag blocks A,B,A,B ; L2 rows A,A,B,B
//   alpha (L1->L2): combine via permlane16_swap ; beta (L2->L1): permlane32.
// Per-step VALU ~= 16 matvec + 3 swap-sum + 1 xF + 2 F + ~1.5 renorm ~ 24.

constexpr int NTAG = 32;
constexpr int TSTART = 30;
constexpr int TSTOP = 31;
constexpr int NB = 1024;
constexpr int NS = 512;

constexpr float LOG2E = 1.44269504088896340736f;
constexpr float LN2   = 0.69314718055994530942f;

typedef unsigned int v2u __attribute__((ext_vector_type(2)));

__device__ __forceinline__ float fexp2(float x) {
#if __has_builtin(__builtin_amdgcn_exp2f)
    return __builtin_amdgcn_exp2f(x);
#else
    return exp2f(x);
#endif
}

// Equal-input permlane swaps: outputs partition {v[j], v[j^K]}, so
// r0 + r1 == v[j] + v[partner] regardless of output order.
__device__ __forceinline__ float swap32_sum(float v) {
    v2u r = __builtin_amdgcn_permlane32_swap(
        __float_as_uint(v), __float_as_uint(v), false, false);
    return __uint_as_float(r.x) + __uint_as_float(r.y);
}
__device__ __forceinline__ float swap16_sum(float v) {
    v2u r = __builtin_amdgcn_permlane16_swap(
        __float_as_uint(v), __float_as_uint(v), false, false);
    return __uint_as_float(r.x) + __uint_as_float(r.y);
}

// 16-term gathered dot product in 16 VALU instructions: DPP row_ror fused
// into v_fmac_f32 (src0 = XV rotated, src1 = table coeff). s_nop 1 guards
// the VALU-write->DPP-read hazard on XV at entry (and ACC at exit for the
// following permlane consumer).
#define MATVEC(ACC, XV, T)                                                    \
    asm("s_nop 1\n\t"                                                         \
        "v_mul_f32 %0, %1, %2\n\t"                                            \
        "v_fmac_f32 %0, %1, %3 row_ror:1 row_mask:0xf bank_mask:0xf\n\t"      \
        "v_fmac_f32 %0, %1, %4 row_ror:2 row_mask:0xf bank_mask:0xf\n\t"      \
        "v_fmac_f32 %0, %1, %5 row_ror:3 row_mask:0xf bank_mask:0xf\n\t"      \
        "v_fmac_f32 %0, %1, %6 row_ror:4 row_mask:0xf bank_mask:0xf\n\t"      \
        "v_fmac_f32 %0, %1, %7 row_ror:5 row_mask:0xf bank_mask:0xf\n\t"      \
        "v_fmac_f32 %0, %1, %8 row_ror:6 row_mask:0xf bank_mask:0xf\n\t"      \
        "v_fmac_f32 %0, %1, %9 row_ror:7 row_mask:0xf bank_mask:0xf\n\t"      \
        "v_fmac_f32 %0, %1, %10 row_ror:8 row_mask:0xf bank_mask:0xf\n\t"     \
        "v_fmac_f32 %0, %1, %11 row_ror:9 row_mask:0xf bank_mask:0xf\n\t"     \
        "v_fmac_f32 %0, %1, %12 row_ror:10 row_mask:0xf bank_mask:0xf\n\t"    \
        "v_fmac_f32 %0, %1, %13 row_ror:11 row_mask:0xf bank_mask:0xf\n\t"    \
        "v_fmac_f32 %0, %1, %14 row_ror:12 row_mask:0xf bank_mask:0xf\n\t"    \
        "v_fmac_f32 %0, %1, %15 row_ror:13 row_mask:0xf bank_mask:0xf\n\t"    \
        "v_fmac_f32 %0, %1, %16 row_ror:14 row_mask:0xf bank_mask:0xf\n\t"    \
        "v_fmac_f32 %0, %1, %17 row_ror:15 row_mask:0xf bank_mask:0xf\n\t"    \
        "s_nop 1"                                                             \
        : "=&v"(ACC)                                                          \
        : "v"(XV), "v"(T[0]), "v"(T[1]), "v"(T[2]), "v"(T[3]),                \
          "v"(T[4]), "v"(T[5]), "v"(T[6]), "v"(T[7]), "v"(T[8]),              \
          "v"(T[9]), "v"(T[10]), "v"(T[11]), "v"(T[12]), "v"(T[13]),          \
          "v"(T[14]), "v"(T[15]))

__global__ __launch_bounds__(64)
void crf_fwd(const float* __restrict__ feats,
             const int*   __restrict__ labels,
             const int*   __restrict__ lengths,
             const float* __restrict__ trans,
             float*       __restrict__ out)
{
    const int j   = threadIdx.x;   // 0..63
    const int j32 = j & 31;
    const int b   = blockIdx.x;

    const int i  = j & 15;          // position within 16-lane row
    const int c1 = j & 16;          // row-parity bit (rows 1,3)
    const int c2 = (j & 32) >> 1;   // half bit as tag-block bit (rows 2,3)

    // Scalar coefficient tables, indexed by rotation amount N (same math as
    // the verified r4 packed tables, unpacked):
    //   alpha (L1->L2): src = ((i-N)&15)|c1 , dst-col = i|c2   -> TmS
    //   beta  (L2->L1): src = ((i-N)&15)|c2 , dst-col = i|c1   -> TsS
    float TmS[16], TsS[16];
    #pragma unroll
    for (int N = 0; N < 16; ++N) {
        int s15 = (i - N) & 15;
        TmS[N] = fexp2(trans[((s15 | c1) << 5) + (i | c2)] * LOG2E);
        TsS[N] = fexp2(trans[((s15 | c2) << 5) + (i | c1)] * LOG2E);
    }

    const int len = lengths[b];
    const float* fb = feats  + (size_t)b * NS * NTAG;
    const int*   lb = labels + (size_t)b * NS;

    // labels for this item, staged into registers (coalesced, off the loop)
    int labr[8];
    #pragma unroll
    for (int k = 0; k < 8; ++k)
        labr[k] = lb[(k << 6) + j];

    // Emission-factor / prefetch index per step parity:
    //   after alpha (odd t): layout L2, tag = i|c2
    //   after beta  (even t): layout L1, tag = j32
    const int fxA = i | c2;
    const int fxB = j32;

    // t = 0 : layout L1, lane j holds P0[j32]
    float x = fexp2((fb[j32] + trans[(TSTART << 5) + j32]) * LOG2E);

    int bits0 = __builtin_amdgcn_readfirstlane(__float_as_int(x));
    int e0    = min(max((bits0 >> 23) & 0xFF, 1), 254);
    int kreg  = e0 - 127;
    int creg  = 0;

    // feats prefetch pipeline (8 deep); slot u serves steps t with t%2==(1+u)%2
    float pf[8];
    #pragma unroll
    for (int u = 0; u < 8; ++u) {
        int tt = min(1 + u, NS - 1);
        pf[u] = fb[(size_t)tt * NTAG + ((u & 1) ? fxB : fxA)];
    }

    const int nsteps = len - 1;        // recursion steps t = 1..len-1
    const int nchunk = nsteps >> 3;
    const int rem    = nsteps & 7;
    int t = 1;

    // TBL: TmS (alpha) or TsS (beta); SW: 16 (alpha) or 32 (beta);
    // RN = 1: fold 2^-kreg into emission factor and re-extract kreg.
    #define CRF_STEP(FEAT, TBL, SW, RN)                                       \
    {                                                                         \
        float F_;                                                             \
        if (RN) {                                                             \
            creg += kreg;                                                     \
            F_ = fexp2(fmaf((FEAT), LOG2E, -(float)kreg));                    \
        } else {                                                              \
            F_ = fexp2((FEAT) * LOG2E);                                       \
        }                                                                     \
        float acc_;                                                           \
        MATVEC(acc_, x, TBL);                                                 \
        float sum2 = (SW == 16) ? swap16_sum(acc_) : swap32_sum(acc_);        \
        x = sum2 * F_;                                                        \
        if (RN) {                                                             \
            int bits_ = __builtin_amdgcn_readfirstlane(__float_as_int(x));    \
            int e_ = min(max((bits_ >> 23) & 0xFF, 1), 254);                  \
            kreg = e_ - 127;                                                  \
        }                                                                     \
    }

    for (int ci = 0; ci < nchunk; ++ci) {
        #pragma unroll
        for (int u = 0; u < 8; ++u) {
            float feat = pf[u];
            int   tp   = min(t + 8, NS - 1);
            pf[u] = fb[(size_t)tp * NTAG + ((u & 1) ? fxB : fxA)];
            if (u & 1) { CRF_STEP(feat, TsS, 32, 1) }   // beta, renorm
            else       { CRF_STEP(feat, TmS, 16, 0) }   // alpha
            ++t;
        }
    }
    // remainder (<8 steps); pf[u] holds feats for t = 1+8*nchunk+u
    #pragma unroll
    for (int u = 0; u < 7; ++u) {
        if (u < rem) {
            if (u & 1) { CRF_STEP(pf[u], TsS, 32, 1) }
            else       { CRF_STEP(pf[u], TmS, 16, 0) }
            ++t;
        }
    }
    #undef CRF_STEP

    // Every tag appears exactly twice across the 64 lanes in BOTH layouts,
    // so the full 64-lane butterfly gives 2*sum(P); subtract ln2.
    float s = x;
    #pragma unroll
    for (int m = 1; m <= 32; m <<= 1)
        s += __shfl_xor(s, m, 64);
    float fwd = (float)creg * LN2 + logf(s) - LN2;

    // ---- gold score: parallel gather tail (latency-tolerant) ----
    float gold = 0.0f;
    #pragma unroll
    for (int k = 0; k < 8; ++k) {
        int tt = (k << 6) + j;
        if (tt < len) {
            int lab_t = labr[k];
            gold += fb[(size_t)tt * NTAG + lab_t];               // emit
            if (tt > 0)
                gold += trans[(lb[tt - 1] << 5) + lab_t];        // pair
            else
                gold += trans[(TSTART << 5) + lab_t];            // start
            if (tt == len - 1)
                gold += trans[(lab_t << 5) + TSTOP];             // stop
        }
    }
    // reduce gold over all 64 lanes (each (b,t) counted once)
    #pragma unroll
    for (int m = 1; m <= 32; m <<= 1)
        gold += __shfl_xor(gold, m, 64);

    if (j == 0)
        atomicAdd(out, (fwd - gold) * (1.0f / 1024.0f));
}

extern "C" void kernel_launch(void* const* d_in, const int* in_sizes, int n_in,
                              void* d_out, int out_size, void* d_ws, size_t ws_size,
                              hipStream_t stream) {
    const float* feats   = (const float*)d_in[0];
    const int*   labels  = (const int*)d_in[1];
    const int*   lengths = (const int*)d_in[2];
    const float* trans   = (const float*)d_in[3];
    float*       out     = (float*)d_out;

    hipMemsetAsync(out, 0, sizeof(float) * (size_t)out_size, stream);
    crf_fwd<<<dim3(NB), dim3(64), 0, stream>>>(feats, labels, lengths, trans, out);
}